// Round 3
// baseline (1146.798 us; speedup 1.0000x reference)
//
#include <hip/hip_runtime.h>
#include <stdint.h>

// Persistent-kernel RNN: 256 wgs (1/CU), W_hh bf16 resident in REGISTERS
// (B-fragments preloaded; 128 VGPR/wave), batch split 16 ways; h exchanged
// via IC with sc0 sc1 + per-group flags.
// R3: wave tile 32m x 32n x K/2 (k-split pairs reduce via LDS), A reads via
// ds_read_b128, B from regs -> per-step LDS traffic ~2x lower than R2.

#define BATCH 512
#define SEQ   256
#define HID   1024
#define CLS   128

#define GB 16          // batch groups
#define GJ 16          // hidden slices
#define BT 32          // batch rows per wg
#define JT 64          // hidden cols per wg
#define WSTR 1028      // W LDS row stride (halves), init staging only
#define SSTR 1032      // h stage row stride (halves): 2064 B, 16B-aligned, +4-bank row shift
#define HSTR 72        // h-store exchange row stride (halves): 144 B, 16B-aligned
#define SMEM_BYTES (JT * WSTR * 2)                 // 131584 B (init W stage dominates)
#define SS_BYTES   (BT * SSTR * 2)                 // 66048
#define RB_OFF     SS_BYTES                        // rbuf: 8 KB f32
#define HS_OFF     (RB_OFF + 8192)                 // hS: 32*72*2 = 4608 B
#define HBUF_HALVES (BATCH * HID)                  // 1 MB per buffer

typedef __attribute__((ext_vector_type(8))) short  bf16x8;
typedef __attribute__((ext_vector_type(4))) short  s16x4;
typedef __attribute__((ext_vector_type(4))) float  f32x4;
typedef __attribute__((ext_vector_type(4))) int    i32x4;
typedef __attribute__((ext_vector_type(2))) unsigned int u32x2;

__device__ __forceinline__ unsigned short f2bf(float f) {
  unsigned int u = __float_as_uint(f);
  u = (u + 0x7FFFu + ((u >> 16) & 1u)) >> 16;   // RNE
  return (unsigned short)u;
}
__device__ __forceinline__ float b2f(short h) {
  return __uint_as_float(((unsigned int)(unsigned short)h) << 16);
}

// ---- device-coherent (IC) accesses ----
__device__ __forceinline__ void store_flag(int* p, int v) {
  asm volatile("global_store_dword %0, %1, off sc0 sc1" :: "v"(p), "v"(v) : "memory");
}
__device__ __forceinline__ int load_flag(const int* p) {
  int v;
  asm volatile("global_load_dword %0, %1, off sc0 sc1\n\t"
               "s_waitcnt vmcnt(0)" : "=v"(v) : "v"(p) : "memory");
  return v;
}
__device__ __forceinline__ void store16(void* p, i32x4 v) {
  asm volatile("global_store_dwordx4 %0, %1, off sc0 sc1" :: "v"(p), "v"(v) : "memory");
}
__device__ __forceinline__ void waitcnt0() {
  asm volatile("s_waitcnt vmcnt(0)" ::: "memory");
}
// raw workgroup barrier: drains LDS ops only — global loads stay in flight
__device__ __forceinline__ void barrier_lgkm() {
  asm volatile("s_waitcnt lgkmcnt(0)\n\ts_barrier" ::: "memory");
}
// issue 4x dwordx4 coherent loads (64 B/thread), no wait
__device__ __forceinline__ void issue4(const void* p, i32x4& a, i32x4& b, i32x4& c, i32x4& d) {
  asm volatile(
    "global_load_dwordx4 %0, %4, off sc0 sc1\n\t"
    "global_load_dwordx4 %1, %4, off offset:128 sc0 sc1\n\t"
    "global_load_dwordx4 %2, %4, off offset:256 sc0 sc1\n\t"
    "global_load_dwordx4 %3, %4, off offset:384 sc0 sc1"
    : "=&v"(a), "=&v"(b), "=&v"(c), "=&v"(d)
    : "v"(p) : "memory");
}
#define DEF_WAIT(NAME, N) \
__device__ __forceinline__ void NAME(i32x4& a, i32x4& b, i32x4& c, i32x4& d) { \
  asm volatile("s_waitcnt vmcnt(" #N ")" : "+v"(a), "+v"(b), "+v"(c), "+v"(d) :: "memory"); \
}
DEF_WAIT(wait_vm12, 12)
DEF_WAIT(wait_vm8, 8)
DEF_WAIT(wait_vm4, 4)
DEF_WAIT(wait_vm0, 0)

__device__ __forceinline__ void wr16(short* p, i32x4 v) {  // 16 B to LDS (16B-aligned)
  union { i32x4 i; bf16x8 v8; } u; u.i = v;
  *(bf16x8*)p = u.v8;
}
__device__ __forceinline__ bf16x8 ld8_64(const short* p) {  // 8 bf16 as 2x b64 (8B-aligned)
  union { bf16x8 v8; s16x4 h[2]; } u;
  u.h[0] = *(const s16x4*)p;
  u.h[1] = *(const s16x4*)(p + 4);
  return u.v8;
}
__device__ __forceinline__ float tanh_fast(float z) {
  float e = __expf(2.f * z);
  return 1.f - 2.f / (e + 1.f);
}

// one k-chunk (256 wide) of this wave's half-K: 8 k-steps, A from LDS b128, B from regs
template<int CK>
__device__ __forceinline__ void mfma_chunk(const short* sA0, const bf16x8 (&fB)[2][16],
                                           f32x4 (&acc)[2][2]) {
#pragma unroll
  for (int ks = 0; ks < 8; ++ks) {
    const int kk = CK * 8 + ks;
    bf16x8 a0 = *(const bf16x8*)(sA0 + CK * 256 + ks * 32);
    bf16x8 a1 = *(const bf16x8*)(sA0 + 16 * SSTR + CK * 256 + ks * 32);
#pragma unroll
    for (int nt = 0; nt < 2; ++nt) {
      acc[0][nt] = __builtin_amdgcn_mfma_f32_16x16x32_bf16(a0, fB[nt][kk], acc[0][nt], 0, 0, 0);
      acc[1][nt] = __builtin_amdgcn_mfma_f32_16x16x32_bf16(a1, fB[nt][kk], acc[1][nt], 0, 0, 0);
    }
  }
}

__global__ void __launch_bounds__(256, 1)
rnn_persistent(const float* __restrict__ x, const float* __restrict__ Whx,
               const float* __restrict__ Whh, const float* __restrict__ bh,
               const float* __restrict__ Wph, const float* __restrict__ bp,
               float* __restrict__ out, unsigned short* hbuf, int* flags)
{
  extern __shared__ short smem[];
  short* sW   = smem;                          // [JT][WSTR] init-only overlay
  short* sS   = smem;                          // [BT][SSTR] h stage (after init)
  float* rbuf = (float*)((char*)smem + RB_OFF);
  short* hS   = (short*)((char*)smem + HS_OFF);

  const int tid  = threadIdx.x;
  const int bg   = blockIdx.x & 15;
  const int jg   = blockIdx.x >> 4;
  const int lane = tid & 63;
  const int wv   = tid >> 6;
  const int l15  = lane & 15;
  const int quad = lane >> 4;
  const int npair = wv & 1;    // n-block: cols [npair*32, +32)
  const int khalf = wv >> 1;   // k-half:  k in [khalf*512, +512)

  // ---- stage W_hh[jg*64 .. +64)[0..1024) into LDS as bf16 (init only) ----
  {
    const int jr = tid >> 2;
    const int kq = tid & 3;
    const float* src = Whh + (jg * JT + jr) * HID + kq * 256;
    short* dst = sW + jr * WSTR + kq * 256;
#pragma unroll 4
    for (int i = 0; i < 64; ++i) {
      float4 f = *(const float4*)(src + i * 4);
      s16x4 h4;
      h4.x = (short)f2bf(f.x); h4.y = (short)f2bf(f.y);
      h4.z = (short)f2bf(f.z); h4.w = (short)f2bf(f.w);
      *(s16x4*)(dst + i * 4) = h4;
    }
  }
  __syncthreads();

  // ---- preload this wave's B-fragments into registers (32 x bf16x8 = 128 VGPR) ----
  // B[k][n]: n = npair*32 + nt*16 + l15 (W_hh row), k = khalf*512 + kk*32 + quad*8
  bf16x8 fB[2][16];
#pragma unroll
  for (int nt = 0; nt < 2; ++nt) {
    const short* bp_ = sW + (npair * 32 + nt * 16 + l15) * WSTR + khalf * 512 + quad * 8;
#pragma unroll
    for (int kk = 0; kk < 16; ++kk)
      fB[nt][kk] = ld8_64(bp_ + kk * 32);
  }
  __syncthreads();   // sW dead; sS overlay may be written from here on

  // epilogue constants (used by khalf==0 waves)
  const int jbase = jg * JT + npair * 32;
  const float whx0 = Whx[jbase + l15];
  const float whx1 = Whx[jbase + 16 + l15];
  const float bh0  = bh[jbase + l15];
  const float bh1  = bh[jbase + 16 + l15];

  // staging thread mapping: 64 B per thread per chunk
  const int sr  = tid >> 3;               // 0..31 stage row
  const int seg = tid & 7;                // 0..7

  int* myflags = flags + bg * 64;         // 16 flags, one 64B line per bg

  const short* sA0 = sS + l15 * SSTR + khalf * 512 + quad * 8;

  for (int t = 0; t < SEQ; ++t) {
    const unsigned short* hin = hbuf + ((t + 1) & 1) * HBUF_HALVES;
    unsigned short*      hout = hbuf + (t & 1) * HBUF_HALVES;

    f32x4 acc[2][2];
#pragma unroll
    for (int mt = 0; mt < 2; ++mt)
#pragma unroll
      for (int nt = 0; nt < 2; ++nt)
        acc[mt][nt] = (f32x4){0.f, 0.f, 0.f, 0.f};

    // x for this step (drained by the spin/syncthreads before the issue window)
    float xv[2][4];
    {
      const float* xp = x + (bg * BT + quad * 4) * SEQ + t;
#pragma unroll
      for (int r = 0; r < 4; ++r) {
        xv[0][r] = xp[r * SEQ];
        xv[1][r] = xp[(16 + r) * SEQ];
      }
    }

    if (t > 0) {
      if (tid < GJ) {
        while (load_flag(myflags + tid) < t) {}
      }
      __syncthreads();   // full drain: vmcnt==0 entering the issue window

      const char* lbase = (const char*)(hin + (bg * BT + sr) * HID) + seg * 16;
      short* sdst = sS + sr * SSTR + seg * 8;

      i32x4 a0, a1, a2, a3, b0, b1, b2, b3, c0, c1, c2, c3, d0, d1, d2, d3;
      issue4(lbase,        a0, a1, a2, a3);   // k chunk 0: [0,256)
      issue4(lbase + 512,  b0, b1, b2, b3);   // k chunk 1: [256,512)
      issue4(lbase + 1024, c0, c1, c2, c3);   // k chunk 2: [512,768)
      issue4(lbase + 1536, d0, d1, d2, d3);   // k chunk 3: [768,1024)

      // chunk 0 -> waves khalf==0
      wait_vm12(a0, a1, a2, a3);
      wr16(sdst, a0); wr16(sdst + 64, a1); wr16(sdst + 128, a2); wr16(sdst + 192, a3);
      barrier_lgkm();
      if (khalf == 0) mfma_chunk<0>(sA0, fB, acc);

      // chunk 1 -> waves khalf==0
      wait_vm8(b0, b1, b2, b3);
      wr16(sdst + 256, b0); wr16(sdst + 320, b1); wr16(sdst + 384, b2); wr16(sdst + 448, b3);
      barrier_lgkm();
      if (khalf == 0) mfma_chunk<1>(sA0, fB, acc);

      // chunk 2 -> waves khalf==1
      wait_vm4(c0, c1, c2, c3);
      wr16(sdst + 512, c0); wr16(sdst + 576, c1); wr16(sdst + 640, c2); wr16(sdst + 704, c3);
      barrier_lgkm();
      if (khalf == 1) mfma_chunk<0>(sA0, fB, acc);

      // chunk 3 -> waves khalf==1
      wait_vm0(d0, d1, d2, d3);
      wr16(sdst + 768, d0); wr16(sdst + 832, d1); wr16(sdst + 896, d2); wr16(sdst + 960, d3);
      barrier_lgkm();
      if (khalf == 1) mfma_chunk<1>(sA0, fB, acc);
    }

    // ---- cross-wave k-reduce: khalf==1 writes partials, khalf==0 adds ----
    if (khalf == 1) {
#pragma unroll
      for (int mt = 0; mt < 2; ++mt)
#pragma unroll
        for (int nt = 0; nt < 2; ++nt)
          *(f32x4*)(rbuf + ((npair * 4 + mt * 2 + nt) * 64 + lane) * 4) = acc[mt][nt];
    }
    barrier_lgkm();

    if (khalf == 0) {
#pragma unroll
      for (int mt = 0; mt < 2; ++mt)
#pragma unroll
        for (int nt = 0; nt < 2; ++nt) {
          f32x4 p = *(const f32x4*)(rbuf + ((npair * 4 + mt * 2 + nt) * 64 + lane) * 4);
          acc[mt][nt] += p;
        }
      // epilogue: h = tanh(acc + x*whx + bh) -> hS
#pragma unroll
      for (int mt = 0; mt < 2; ++mt) {
#pragma unroll
        for (int r = 0; r < 4; ++r) {
          const int row = mt * 16 + quad * 4 + r;
          float z0 = acc[mt][0][r] + xv[mt][r] * whx0 + bh0;
          hS[row * HSTR + npair * 32 + l15] = (short)f2bf(tanh_fast(z0));
          float z1 = acc[mt][1][r] + xv[mt][r] * whx1 + bh1;
          hS[row * HSTR + npair * 32 + 16 + l15] = (short)f2bf(tanh_fast(z1));
        }
      }
    }
    barrier_lgkm();

    // coalesced 16B store of the 32x64 h tile
    {
      union { bf16x8 v8; i32x4 i; } u;
      u.v8 = *(const bf16x8*)(hS + sr * HSTR + seg * 8);
      unsigned short* dst = hout + (bg * BT + sr) * HID + jg * JT + seg * 8;
      store16(dst, u.i);
    }
    waitcnt0();          // this thread's store retired at IC
    barrier_lgkm();      // all threads retired before the flag release
    if (tid == 0) store_flag(myflags + jg, t + 1);
  }

  // ---- output head: out[b, jg*8+cc] = h_last . W_ph[c] + b_p ----
  if (tid < GJ) {
    while (load_flag(myflags + tid) < SEQ) {}
  }
  __syncthreads();

  const unsigned short* hlast = hbuf + ((SEQ - 1) & 1) * HBUF_HALVES;
  {
    const char* lbase = (const char*)(hlast + (bg * BT + sr) * HID) + seg * 16;
    short* sdst = sS + sr * SSTR + seg * 8;
    i32x4 p0, p1, p2, p3;
#pragma unroll
    for (int c = 0; c < 4; ++c) {
      issue4(lbase + c * 512, p0, p1, p2, p3);
      waitcnt0();
      wr16(sdst + c * 256, p0); wr16(sdst + c * 256 + 64, p1);
      wr16(sdst + c * 256 + 128, p2); wr16(sdst + c * 256 + 192, p3);
    }
  }
  __syncthreads();

  const int cc = tid & 7;
  const int cg = jg * 8 + cc;
  const int hr = tid >> 3;
  float acc = 0.f;
  const float* wp = Wph + cg * HID;
  const short* hs = sS + hr * SSTR;
#pragma unroll 8
  for (int k4 = 0; k4 < 256; ++k4) {
    float4 w  = *(const float4*)(wp + k4 * 4);
    s16x4 hv  = *(const s16x4*)(hs + k4 * 4);
    acc += b2f(hv.x) * w.x + b2f(hv.y) * w.y + b2f(hv.z) * w.z + b2f(hv.w) * w.w;
  }
  out[(bg * BT + hr) * CLS + cg] = acc + bp[cg];
}

extern "C" void kernel_launch(void* const* d_in, const int* in_sizes, int n_in,
                              void* d_out, int out_size, void* d_ws, size_t ws_size,
                              hipStream_t stream) {
  const float* x   = (const float*)d_in[0];
  const float* Whx = (const float*)d_in[1];
  const float* Whh = (const float*)d_in[2];
  const float* bh  = (const float*)d_in[3];
  const float* Wph = (const float*)d_in[4];
  const float* bp  = (const float*)d_in[5];
  float* out = (float*)d_out;

  unsigned short* hbuf = (unsigned short*)d_ws;
  int* flags = (int*)((char*)d_ws + (size_t)2 * HBUF_HALVES * 2);

  hipFuncSetAttribute(reinterpret_cast<const void*>(rnn_persistent),
                      hipFuncAttributeMaxDynamicSharedMemorySize, SMEM_BYTES);

  rnn_persistent<<<dim3(GB * GJ), dim3(256), SMEM_BYTES, stream>>>(
      x, Whx, Whh, bh, Wph, bp, out, hbuf, flags);
}